// Round 6
// baseline (2616.234 us; speedup 1.0000x reference)
//
#include <hip/hip_runtime.h>

#define NB   16          // batch
#define NC   256         // channels
#define NHW  4096        // H*W
#define MTOT (NB*NHW)    // 65536 rows in [M, C] layout
#define FF1C 1360        // 2*NCH
#define NCHH 680
#define KPAD 704         // padded K for gemm2 (680 -> 704 = 11*64)
#define MCHUNK 16384     // 4 batches per FF chunk

typedef unsigned short u16;
typedef __attribute__((ext_vector_type(8))) short bf16x8;
typedef __attribute__((ext_vector_type(4))) float f32x4;
typedef __attribute__((ext_vector_type(4))) unsigned short u16x4;

__device__ __forceinline__ float bf2f(u16 u){
    union { unsigned int ui; float f; } c; c.ui = ((unsigned int)u) << 16; return c.f;
}
__device__ __forceinline__ u16 f2bf(float f){
    union { float f; unsigned int u; } c; c.f = f;
    unsigned int x = c.u;
    unsigned int r = (x + 0x7fffu + ((x >> 16) & 1u)) >> 16;
    return (u16)r;
}
__device__ __forceinline__ float gelu_f(float x){
    return 0.5f * x * (1.f + erff(x * 0.70710678118654752f));
}
__device__ __forceinline__ float softplus_f(float x){
    return fmaxf(x, 0.f) + log1pf(expf(-fabsf(x)));
}

// ---------------- small utility kernels ----------------
__global__ __launch_bounds__(256) void cvt_w(const float* __restrict__ s, u16* __restrict__ d, int n){
    int i = blockIdx.x * 256 + threadIdx.x;
    if (i < n) d[i] = f2bf(s[i]);
}
// ff_w2 [256][680] fp32 -> [256][704] bf16 zero-padded
__global__ __launch_bounds__(256) void cvt_w2pad(const float* __restrict__ s, u16* __restrict__ d){
    int i = blockIdx.x * 256 + threadIdx.x;
    if (i < 256 * KPAD){
        int r = i / KPAD, c = i - r * KPAD;
        d[i] = (c < NCHH) ? f2bf(s[r * NCHH + c]) : (u16)0;
    }
}
__global__ __launch_bounds__(256) void zero_buf(float* __restrict__ p, int n){
    int i = blockIdx.x * 256 + threadIdx.x;
    if (i < n) p[i] = 0.f;
}

// ---------------- instance norm #1 (on NCHW x) ----------------
__global__ __launch_bounds__(256) void inorm_stats(const float* __restrict__ x,
                                                   float* __restrict__ mean, float* __restrict__ rstd){
    int bc = blockIdx.x;   // b*256+c
    const float4* p = (const float4*)(x + (size_t)bc * NHW);
    float s = 0.f, s2 = 0.f;
    for (int i = threadIdx.x; i < NHW/4; i += 256){
        float4 v = p[i];
        s  += v.x + v.y + v.z + v.w;
        s2 += v.x*v.x + v.y*v.y + v.z*v.z + v.w*v.w;
    }
    for (int o = 32; o; o >>= 1){ s += __shfl_down(s, o); s2 += __shfl_down(s2, o); }
    __shared__ float a[4], a2[4];
    int w = threadIdx.x >> 6;
    if ((threadIdx.x & 63) == 0){ a[w] = s; a2[w] = s2; }
    __syncthreads();
    if (threadIdx.x == 0){
        s = a[0]+a[1]+a[2]+a[3]; s2 = a2[0]+a2[1]+a2[2]+a2[3];
        float mu = s * (1.f/NHW);
        float var = s2 * (1.f/NHW) - mu*mu;
        mean[bc] = mu; rstd[bc] = rsqrtf(var + 1e-5f);
    }
}

// NCHW fp32 -> [M,C] bf16 normalized (xn)
__global__ __launch_bounds__(256) void transpose_norm(const float* __restrict__ x,
        const float* __restrict__ mean, const float* __restrict__ rstd,
        u16* __restrict__ xn){
    int bid = blockIdx.x;            // b(4b) ctile(2b) ntile(6b)
    int b = bid >> 8; int ct = (bid >> 6) & 3; int nt = bid & 63;
    __shared__ float t[64][65];
    int nl = threadIdx.x & 63; int cw = threadIdx.x >> 6;
    const float* xp = x + ((size_t)b*NC + ct*64) * NHW + nt*64;
    #pragma unroll
    for (int i = 0; i < 16; i++){
        int cl = cw + i*4;
        t[cl][nl] = xp[(size_t)cl * NHW + nl];
    }
    __syncthreads();
    int cl = threadIdx.x & 63; int nw = threadIdx.x >> 6;
    int cg = ct*64 + cl;
    float mu = mean[b*NC + cg], rs = rstd[b*NC + cg];
    size_t obase = ((size_t)b*NHW + nt*64) * NC + ct*64;
    #pragma unroll
    for (int i = 0; i < 16; i++){
        int n2 = nw + i*4;
        float v = t[cl][n2];
        xn[obase + (size_t)n2*NC + cl] = f2bf((v - mu) * rs);
    }
}

// ---------------- GEMM: Y = act(X[M][K] @ W[Nc][K]^T + bias) (+res) ----------------
// ACT: 0 none, 1 gelu, 2 softplus
// RES: 0 none, 1 fp32 [M,C] (stride NC, with row_off), 2 fp32 NCHW (x, with row_off)
// OUT: 0 fp32 [M,C] (stride NC), 1 bf16 [M,*] (stride Nstride), 2 fp32 NCHW (with row_off)
template<int ACT, int RES, int OUT, bool HAS_BIAS, bool NEDGE>
__global__ __launch_bounds__(256, 2) void gemm_bf16(
        const u16* __restrict__ X, const u16* __restrict__ Wt,
        const float* __restrict__ bias, const float* __restrict__ res,
        void* __restrict__ Yout, int Ncols, int K, int Nstride, int row_off){
    __shared__ u16 As[128*64];
    __shared__ u16 Bs[128*64];
    const int tid  = threadIdx.x;
    const int row0 = blockIdx.x * 128;
    const int col0 = blockIdx.y * 128;
    const int lane = tid & 63;
    const int wave = tid >> 6;
    const int wr = (wave >> 1) * 64;
    const int wc = (wave & 1) * 64;
    f32x4 acc[4][4] = {};
    const int kc  = (tid & 7) * 8;   // k element offset in 64-wide tile
    const int rA  = tid >> 3;        // 0..31
    const int kcb = kc * 2;          // byte offset
    const bf16x8 vzero = {0,0,0,0,0,0,0,0};
    for (int kt = 0; kt < K; kt += 64){
        #pragma unroll
        for (int i = 0; i < 4; i++){
            int r = rA + i*32;
            bf16x8 v = *(const bf16x8*)(X + (size_t)(row0 + r) * K + kt + kc);
            *(bf16x8*)((char*)As + r*128 + (kcb ^ ((r & 7) << 4))) = v;
        }
        #pragma unroll
        for (int i = 0; i < 4; i++){
            int r = rA + i*32;
            int gc = col0 + r;
            bf16x8 v = vzero;
            if (!NEDGE || gc < Ncols) v = *(const bf16x8*)(Wt + (size_t)gc * K + kt + kc);
            *(bf16x8*)((char*)Bs + r*128 + (kcb ^ ((r & 7) << 4))) = v;
        }
        __syncthreads();
        #pragma unroll
        for (int ks = 0; ks < 2; ks++){
            const int kb = ks*64 + ((lane >> 4) * 16);
            bf16x8 af[4], bv[4];
            #pragma unroll
            for (int m = 0; m < 4; m++){
                int r = wr + m*16 + (lane & 15);
                af[m] = *(const bf16x8*)((const char*)As + r*128 + (kb ^ ((r & 7) << 4)));
            }
            #pragma unroll
            for (int nn = 0; nn < 4; nn++){
                int r = wc + nn*16 + (lane & 15);
                bv[nn] = *(const bf16x8*)((const char*)Bs + r*128 + (kb ^ ((r & 7) << 4)));
            }
            #pragma unroll
            for (int m = 0; m < 4; m++)
                #pragma unroll
                for (int nn = 0; nn < 4; nn++)
                    acc[m][nn] = __builtin_amdgcn_mfma_f32_16x16x32_bf16(af[m], bv[nn], acc[m][nn], 0, 0, 0);
        }
        __syncthreads();
    }
    const int lr = (lane >> 4) * 4;
    const int lc = lane & 15;
    #pragma unroll
    for (int nn = 0; nn < 4; nn++){
        int gc = col0 + wc + nn*16 + lc;
        if (NEDGE && gc >= Ncols) continue;
        float bvl = HAS_BIAS ? bias[gc] : 0.f;
        #pragma unroll
        for (int m = 0; m < 4; m++){
            int nb = row0 + wr + m*16 + lr;     // local row base; rows nb..nb+3
            float4 rv;
            if (RES == 2){
                int gr = nb + row_off;
                int bb = gr >> 12, n = gr & 4095;
                rv = *(const float4*)(res + ((size_t)bb*NC + gc)*NHW + n);
            }
            float vout[4];
            #pragma unroll
            for (int r = 0; r < 4; r++){
                float v = acc[m][nn][r] + bvl;
                if (ACT == 1) v = gelu_f(v);
                else if (ACT == 2) v = softplus_f(v);
                if (RES == 1) v += res[(size_t)(nb + r + row_off) * NC + gc];
                if (RES == 2) v += ((const float*)&rv)[r];
                vout[r] = v;
            }
            if (OUT == 0){
                #pragma unroll
                for (int r = 0; r < 4; r++)
                    ((float*)Yout)[(size_t)(nb + r) * NC + gc] = vout[r];
            } else if (OUT == 1){
                #pragma unroll
                for (int r = 0; r < 4; r++)
                    ((u16*)Yout)[(size_t)(nb + r) * Nstride + gc] = f2bf(vout[r]);
            } else {
                int gr = nb + row_off;
                int bb = gr >> 12, n = gr & 4095;
                float4 o; o.x = vout[0]; o.y = vout[1]; o.z = vout[2]; o.w = vout[3];
                *(float4*)(((float*)Yout) + ((size_t)bb*NC + gc)*NHW + n) = o;
            }
        }
    }
}

// ---------------- attention: kv = K^T V (per b,h), ksum ----------------
__global__ __launch_bounds__(256) void kv_kernel(const u16* __restrict__ kbf, const u16* __restrict__ vbf,
                                                 float* __restrict__ kv, float* __restrict__ ksum){
    int bh = blockIdx.x >> 3; int chunk = blockIdx.x & 7;
    int b = bh >> 2, h = bh & 3;
    size_t base = ((size_t)b*NHW + (size_t)chunk*512) * NC + h*64;
    __shared__ float ks[64][65];
    __shared__ float vs[64][68];
    int c  = threadIdx.x & 63;
    int d0 = (threadIdx.x >> 6) * 16;
    float acc[16];
    #pragma unroll
    for (int j = 0; j < 16; j++) acc[j] = 0.f;
    float ksacc = 0.f;
    for (int t = 0; t < 8; t++){
        __syncthreads();
        #pragma unroll
        for (int i = 0; i < 16; i++){
            int idx = threadIdx.x + i*256; int nl = idx >> 6, cc = idx & 63;
            size_t gpos = base + ((size_t)t*64 + nl) * NC + cc;
            ks[nl][cc] = bf2f(kbf[gpos]);
            vs[nl][cc] = bf2f(vbf[gpos]);
        }
        __syncthreads();
        for (int nl = 0; nl < 64; nl++){
            float kvl = ks[nl][c];
            const float4* vr = (const float4*)&vs[nl][d0];
            float4 v0 = vr[0], v1 = vr[1], v2 = vr[2], v3 = vr[3];
            acc[0]+=kvl*v0.x; acc[1]+=kvl*v0.y; acc[2]+=kvl*v0.z; acc[3]+=kvl*v0.w;
            acc[4]+=kvl*v1.x; acc[5]+=kvl*v1.y; acc[6]+=kvl*v1.z; acc[7]+=kvl*v1.w;
            acc[8]+=kvl*v2.x; acc[9]+=kvl*v2.y; acc[10]+=kvl*v2.z; acc[11]+=kvl*v2.w;
            acc[12]+=kvl*v3.x; acc[13]+=kvl*v3.y; acc[14]+=kvl*v3.z; acc[15]+=kvl*v3.w;
        }
        if (threadIdx.x < 64){
            #pragma unroll 8
            for (int nl = 0; nl < 64; nl++) ksacc += ks[nl][threadIdx.x];
        }
    }
    float* kvp = kv + (size_t)bh*4096 + c*64 + d0;
    #pragma unroll
    for (int j = 0; j < 16; j++) atomicAdd(&kvp[j], acc[j]);
    if (threadIdx.x < 64) atomicAdd(&ksum[bh*64 + threadIdx.x], ksacc);
}

// out[n][d] = ((q . kv)/8 + v) * z * g  -> ao bf16
__global__ __launch_bounds__(256) void attn_out_kernel(const u16* __restrict__ qbf, const u16* __restrict__ vbf,
        const u16* __restrict__ gbf, const float* __restrict__ kv, const float* __restrict__ ksum,
        u16* __restrict__ ao){
    int bid = blockIdx.x;
    int b = bid >> 8; int h = (bid >> 6) & 3; int ncn = bid & 63;
    __shared__ float kvs[64][65];
    __shared__ float qs[64][65];
    __shared__ float zs[64];
    size_t base = ((size_t)b*NHW + ncn*64) * NC + h*64;
    const float* kvp = kv + ((size_t)(b*4 + h)) * 4096;
    #pragma unroll
    for (int i = 0; i < 16; i++){
        int idx = threadIdx.x + i*256;
        kvs[idx >> 6][idx & 63] = kvp[idx];
    }
    #pragma unroll
    for (int i = 0; i < 16; i++){
        int idx = threadIdx.x + i*256; int nl = idx >> 6, cc = idx & 63;
        qs[nl][cc] = bf2f(qbf[base + (size_t)nl*NC + cc]);
    }
    __syncthreads();
    if (threadIdx.x < 64){
        const float* kss = ksum + (b*4 + h) * 64;
        float s = 0.f;
        for (int cc = 0; cc < 64; cc++) s += qs[threadIdx.x][cc] * kss[cc];
        zs[threadIdx.x] = 1.f / (s * 0.125f + 4096.f);
    }
    __syncthreads();
    int d = threadIdx.x & 63; int ng = threadIdx.x >> 6;
    for (int nl = ng; nl < 64; nl += 4){
        float s = 0.f;
        #pragma unroll 8
        for (int cc = 0; cc < 64; cc++) s += qs[nl][cc] * kvs[cc][d];
        size_t gi = base + (size_t)nl*NC + d;
        float o = (s * 0.125f + bf2f(vbf[gi])) * zs[nl];
        ao[gi] = f2bf(o * bf2f(gbf[gi]));
    }
}

// ---------------- instance norm #2 (on [M,C] fp32 attn) ----------------
__global__ __launch_bounds__(256) void colstats_part(const float* __restrict__ a, float* __restrict__ part){
    int b = blockIdx.x >> 5, seg = blockIdx.x & 31;
    const float* p = a + ((size_t)b*NHW + seg*128) * NC + threadIdx.x;
    float s = 0.f, s2 = 0.f;
    for (int r = 0; r < 128; r++){ float v = p[(size_t)r*NC]; s += v; s2 += v*v; }
    part[((size_t)blockIdx.x*256 + threadIdx.x)*2]     = s;
    part[((size_t)blockIdx.x*256 + threadIdx.x)*2 + 1] = s2;
}
__global__ __launch_bounds__(256) void colstats_final(const float* __restrict__ part,
        float* __restrict__ mean, float* __restrict__ rstd){
    int b = blockIdx.x; int c = threadIdx.x;
    float s = 0.f, s2 = 0.f;
    for (int i = 0; i < 32; i++){
        s  += part[(((size_t)b*32 + i)*256 + c)*2];
        s2 += part[(((size_t)b*32 + i)*256 + c)*2 + 1];
    }
    float mu = s * (1.f/NHW);
    float var = s2 * (1.f/NHW) - mu*mu;
    mean[b*NC + c] = mu; rstd[b*NC + c] = rsqrtf(var + 1e-5f);
}
__global__ __launch_bounds__(256) void norm_cast(const float4* __restrict__ a, const float* __restrict__ mean,
        const float* __restrict__ rstd, u16x4* __restrict__ yn){
    for (size_t gi = (size_t)blockIdx.x*256 + threadIdx.x; gi < (size_t)(MTOT)*64; gi += (size_t)gridDim.x*256){
        float4 v = a[gi];
        int c4 = (int)(gi & 63) * 4;
        int b  = (int)(gi >> 18);
        const float* mp = mean + b*NC + c4;
        const float* rp = rstd + b*NC + c4;
        u16x4 o;
        o[0] = f2bf((v.x - mp[0]) * rp[0]);
        o[1] = f2bf((v.y - mp[1]) * rp[1]);
        o[2] = f2bf((v.z - mp[2]) * rp[2]);
        o[3] = f2bf((v.w - mp[3]) * rp[3]);
        yn[gi] = o;
    }
}

// ---------------- depthwise 3x3 + gelu-gate (4-batch chunk, local rows) ----------------
__global__ __launch_bounds__(256) void dw_kernel(const u16* __restrict__ ff1, const float* __restrict__ wd,
                                                 u16* __restrict__ ffg){
    int b = blockIdx.x >> 6;   // local batch 0..3
    int y = blockIdx.x & 63;
    size_t nbase = (size_t)b*NHW + y*64;
    for (int x = 0; x < 64; x++){
        for (int ch = threadIdx.x; ch < KPAD; ch += 256){
            size_t outi = (nbase + x) * KPAD + ch;
            if (ch >= NCHH){ ffg[outi] = 0; continue; }
            float a1 = 0.f, a2 = 0.f;
            const float* w1 = wd + ch*9;
            const float* w2 = wd + (ch + NCHH)*9;
            #pragma unroll
            for (int dy = -1; dy <= 1; dy++){
                int yy = y + dy; if (yy < 0 || yy >= 64) continue;
                #pragma unroll
                for (int dx = -1; dx <= 1; dx++){
                    int xx = x + dx; if (xx < 0 || xx >= 64) continue;
                    size_t p = ((size_t)b*NHW + yy*64 + xx) * FF1C;
                    int wi = (dy + 1)*3 + (dx + 1);
                    a1 += w1[wi] * bf2f(ff1[p + ch]);
                    a2 += w2[wi] * bf2f(ff1[p + NCHH + ch]);
                }
            }
            ffg[outi] = f2bf(gelu_f(a1) * a2);
        }
    }
}

extern "C" void kernel_launch(void* const* d_in, const int* in_sizes, int n_in,
                              void* d_out, int out_size, void* d_ws, size_t ws_size,
                              hipStream_t stream){
    const float* x    = (const float*)d_in[0];
    const float* wq1  = (const float*)d_in[1];
    const float* wq2  = (const float*)d_in[2];
    const float* wk1  = (const float*)d_in[3];
    const float* wk2  = (const float*)d_in[4];
    const float* wv   = (const float*)d_in[5];
    const float* wg   = (const float*)d_in[6];
    const float* wo   = (const float*)d_in[7];
    const float* bq1  = (const float*)d_in[8];
    const float* bq2  = (const float*)d_in[9];
    const float* bk1  = (const float*)d_in[10];
    const float* bk2  = (const float*)d_in[11];
    const float* bv   = (const float*)d_in[12];
    const float* bg   = (const float*)d_in[13];
    const float* bo   = (const float*)d_in[14];
    const float* ffw1 = (const float*)d_in[15];
    const float* ffwd = (const float*)d_in[16];
    const float* ffw2 = (const float*)d_in[17];

    char* ws = (char*)d_ws;
    size_t off = 0;
    auto alloc = [&](size_t bytes) -> char* {
        char* p = ws + off;
        off += (bytes + 255) & ~(size_t)255;
        return p;
    };
    const size_t MC = (size_t)MTOT * NC;          // 16,777,216 elements

    u16* wq1b  = (u16*)alloc(65536*2);
    u16* wq2b  = (u16*)alloc(65536*2);
    u16* wk1b  = (u16*)alloc(65536*2);
    u16* wk2b  = (u16*)alloc(65536*2);
    u16* wvb   = (u16*)alloc(65536*2);
    u16* wgb   = (u16*)alloc(65536*2);
    u16* wob   = (u16*)alloc(65536*2);
    u16* ffw1b = (u16*)alloc((size_t)FF1C*256*2);
    u16* ffw2b = (u16*)alloc((size_t)256*KPAD*2);
    float* mean1 = (float*)alloc(4096*4);
    float* rstd1 = (float*)alloc(4096*4);
    float* mean2 = (float*)alloc(4096*4);
    float* rstd2 = (float*)alloc(4096*4);
    float* part  = (float*)alloc((size_t)512*256*2*4);
    float* kv    = (float*)alloc((size_t)64*4096*4);   // 1 MB, 256-aligned
    float* ksum  = (float*)alloc(4096*4);              // contiguous after kv
    float* attn  = (float*)alloc(MC*4);                // 64 MB fp32 [M,C]
    // 4-slot bf16 pool, 32 MB each (128 MB total)
    char* pool = alloc((size_t)4 * MC * 2);
    u16* s1 = (u16*)pool;            // xn -> ao -> yn
    u16* s2 = s1 + MC;               // kpre -> v ; later ff1c start
    u16* s3 = s2 + MC;               // k -> qpre -> g
    u16* s4 = s3 + MC;               // q ; later part of ffg region
    u16* xn = s1,  *ao = s1,  *yn = s1;
    u16* ff1c = s2;                                    // 16384*1360*2 = 44.5 MB (spans s2 + part of s3)
    u16* ffgc = (u16*)(pool + (size_t)80*1024*1024);   // 16384*704*2 = 23 MB (inside s3/s4, after ff1c)

    (void)ws_size; (void)in_sizes; (void)n_in; (void)out_size;

    // weights -> bf16
    cvt_w<<<256, 256, 0, stream>>>(wq1, wq1b, 65536);
    cvt_w<<<256, 256, 0, stream>>>(wq2, wq2b, 65536);
    cvt_w<<<256, 256, 0, stream>>>(wk1, wk1b, 65536);
    cvt_w<<<256, 256, 0, stream>>>(wk2, wk2b, 65536);
    cvt_w<<<256, 256, 0, stream>>>(wv,  wvb,  65536);
    cvt_w<<<256, 256, 0, stream>>>(wg,  wgb,  65536);
    cvt_w<<<256, 256, 0, stream>>>(wo,  wob,  65536);
    cvt_w<<<(FF1C*256+255)/256, 256, 0, stream>>>(ffw1, ffw1b, FF1C*256);
    cvt_w2pad<<<(256*KPAD+255)/256, 256, 0, stream>>>(ffw2, ffw2b);

    // instance norm #1 + transpose to [M,C] bf16
    inorm_stats<<<4096, 256, 0, stream>>>(x, mean1, rstd1);
    transpose_norm<<<4096, 256, 0, stream>>>(x, mean1, rstd1, xn);

    // zero kv+ksum (contiguous: 262144 + 4096 floats)
    zero_buf<<<(266240+255)/256, 256, 0, stream>>>(kv, 266240);

    // attention branch: k-chain, v, kv, q-chain, g  (4-slot schedule)
    gemm_bf16<1,0,1,true,false><<<dim3(512,2), 256, 0, stream>>>(xn, wk1b, bk1, nullptr, s2, 256, 256, 256, 0); // kpre->s2
    gemm_bf16<2,0,1,true,false><<<dim3(512,2), 256, 0, stream>>>(s2, wk2b, bk2, nullptr, s3, 256, 256, 256, 0); // k->s3
    gemm_bf16<1,0,1,true,false><<<dim3(512,2), 256, 0, stream>>>(xn, wvb,  bv,  nullptr, s2, 256, 256, 256, 0); // v->s2
    kv_kernel<<<512, 256, 0, stream>>>(s3, s2, kv, ksum);                                                        // k,v
    gemm_bf16<1,0,1,true,false><<<dim3(512,2), 256, 0, stream>>>(xn, wq1b, bq1, nullptr, s3, 256, 256, 256, 0); // qpre->s3
    gemm_bf16<2,0,1,true,false><<<dim3(512,2), 256, 0, stream>>>(s3, wq2b, bq2, nullptr, s4, 256, 256, 256, 0); // q->s4
    gemm_bf16<1,0,1,true,false><<<dim3(512,2), 256, 0, stream>>>(xn, wgb,  bg,  nullptr, s3, 256, 256, 256, 0); // g->s3
    attn_out_kernel<<<4096, 256, 0, stream>>>(s4, s2, s3, kv, ksum, ao);                                         // q,v,g -> ao(s1)

    // wo conv + bias + residual(x, NCHW direct) -> attn fp32 [M,C]
    gemm_bf16<0,2,0,true,false><<<dim3(512,2), 256, 0, stream>>>(ao, wob, bo, x, attn, 256, 256, 256, 0);

    // instance norm #2
    colstats_part<<<512, 256, 0, stream>>>(attn, part);
    colstats_final<<<16, 256, 0, stream>>>(part, mean2, rstd2);
    norm_cast<<<4096, 256, 0, stream>>>((const float4*)attn, mean2, rstd2, (u16x4*)yn);

    // FeedForward in 4 chunks of 4 batches (16384 rows each)
    for (int c = 0; c < 4; c++){
        const u16* ync = yn + (size_t)c * MCHUNK * NC;
        gemm_bf16<0,0,1,false,true><<<dim3(128,11), 256, 0, stream>>>(ync, ffw1b, nullptr, nullptr, ff1c, FF1C, 256, FF1C, 0);
        dw_kernel<<<256, 256, 0, stream>>>(ff1c, ffwd, ffgc);
        gemm_bf16<0,1,2,false,false><<<dim3(128,2), 256, 0, stream>>>(ffgc, ffw2b, nullptr, attn, (float*)d_out, 256, KPAD, 256, c*MCHUNK);
    }
}

// Round 11
// 1138.488 us; speedup vs baseline: 2.2980x; 2.2980x over previous
//
#include <hip/hip_runtime.h>

#define NB   16          // batch
#define NC   256         // channels
#define NHW  4096        // H*W
#define MTOT (NB*NHW)    // 65536 rows in [M, C] layout
#define FF1C 1360        // 2*NCH
#define NCHH 680
#define KPAD 704         // padded K for gemm2 (680 -> 704 = 11*64)
#define MCHUNK 16384     // 4 batches per FF chunk

typedef unsigned short u16;
typedef __attribute__((ext_vector_type(8))) short bf16x8;
typedef __attribute__((ext_vector_type(4))) float f32x4;
typedef __attribute__((ext_vector_type(4))) unsigned short u16x4;

__device__ __forceinline__ float bf2f(u16 u){
    union { unsigned int ui; float f; } c; c.ui = ((unsigned int)u) << 16; return c.f;
}
__device__ __forceinline__ u16 f2bf(float f){
    union { float f; unsigned int u; } c; c.f = f;
    unsigned int x = c.u;
    unsigned int r = (x + 0x7fffu + ((x >> 16) & 1u)) >> 16;
    return (u16)r;
}
__device__ __forceinline__ float gelu_f(float x){
    return 0.5f * x * (1.f + erff(x * 0.70710678118654752f));
}
__device__ __forceinline__ float softplus_f(float x){
    return fmaxf(x, 0.f) + log1pf(expf(-fabsf(x)));
}

// ---------------- small utility kernels ----------------
__global__ __launch_bounds__(256) void cvt_w(const float* __restrict__ s, u16* __restrict__ d, int n){
    int i = blockIdx.x * 256 + threadIdx.x;
    if (i < n) d[i] = f2bf(s[i]);
}
// ff_w2 [256][680] fp32 -> [256][704] bf16 zero-padded
__global__ __launch_bounds__(256) void cvt_w2pad(const float* __restrict__ s, u16* __restrict__ d){
    int i = blockIdx.x * 256 + threadIdx.x;
    if (i < 256 * KPAD){
        int r = i / KPAD, c = i - r * KPAD;
        d[i] = (c < NCHH) ? f2bf(s[r * NCHH + c]) : (u16)0;
    }
}
// ff_wd [1360][9] fp32 -> wdt [9][2][680] fp32 (tap-major, halves split)
__global__ __launch_bounds__(256) void cvt_wdt(const float* __restrict__ s, float* __restrict__ d){
    int i = blockIdx.x * 256 + threadIdx.x;
    if (i < FF1C * 9){
        int ch = i / 9, wi = i - ch * 9;
        int half = (ch >= NCHH) ? 1 : 0;
        int c = ch - half * NCHH;
        d[(wi * 2 + half) * NCHH + c] = s[i];
    }
}
__global__ __launch_bounds__(256) void zero_buf(float* __restrict__ p, int n){
    int i = blockIdx.x * 256 + threadIdx.x;
    if (i < n) p[i] = 0.f;
}

// ---------------- instance norm #1 (on NCHW x) ----------------
__global__ __launch_bounds__(256) void inorm_stats(const float* __restrict__ x,
                                                   float* __restrict__ mean, float* __restrict__ rstd){
    int bc = blockIdx.x;   // b*256+c
    const float4* p = (const float4*)(x + (size_t)bc * NHW);
    float s = 0.f, s2 = 0.f;
    for (int i = threadIdx.x; i < NHW/4; i += 256){
        float4 v = p[i];
        s  += v.x + v.y + v.z + v.w;
        s2 += v.x*v.x + v.y*v.y + v.z*v.z + v.w*v.w;
    }
    for (int o = 32; o; o >>= 1){ s += __shfl_down(s, o); s2 += __shfl_down(s2, o); }
    __shared__ float a[4], a2[4];
    int w = threadIdx.x >> 6;
    if ((threadIdx.x & 63) == 0){ a[w] = s; a2[w] = s2; }
    __syncthreads();
    if (threadIdx.x == 0){
        s = a[0]+a[1]+a[2]+a[3]; s2 = a2[0]+a2[1]+a2[2]+a2[3];
        float mu = s * (1.f/NHW);
        float var = s2 * (1.f/NHW) - mu*mu;
        mean[bc] = mu; rstd[bc] = rsqrtf(var + 1e-5f);
    }
}

// NCHW fp32 -> [M,C] bf16 normalized (xn)
__global__ __launch_bounds__(256) void transpose_norm(const float* __restrict__ x,
        const float* __restrict__ mean, const float* __restrict__ rstd,
        u16* __restrict__ xn){
    int bid = blockIdx.x;            // b(4b) ctile(2b) ntile(6b)
    int b = bid >> 8; int ct = (bid >> 6) & 3; int nt = bid & 63;
    __shared__ float t[64][65];
    int nl = threadIdx.x & 63; int cw = threadIdx.x >> 6;
    const float* xp = x + ((size_t)b*NC + ct*64) * NHW + nt*64;
    #pragma unroll
    for (int i = 0; i < 16; i++){
        int cl = cw + i*4;
        t[cl][nl] = xp[(size_t)cl * NHW + nl];
    }
    __syncthreads();
    int cl = threadIdx.x & 63; int nw = threadIdx.x >> 6;
    int cg = ct*64 + cl;
    float mu = mean[b*NC + cg], rs = rstd[b*NC + cg];
    size_t obase = ((size_t)b*NHW + nt*64) * NC + ct*64;
    #pragma unroll
    for (int i = 0; i < 16; i++){
        int n2 = nw + i*4;
        float v = t[cl][n2];
        xn[obase + (size_t)n2*NC + cl] = f2bf((v - mu) * rs);
    }
}

// ---------------- GEMM: Y = act(X[M][K] @ W[Nc][K]^T + bias) (+res) ----------------
// ACT: 0 none, 1 gelu, 2 softplus
// RES: 0 none, 1 fp32 [M,C] (stride NC, with row_off), 2 fp32 NCHW (x, with row_off)
// OUT: 0 fp32 [M,C] (stride NC), 1 bf16 [M,*] (stride Nstride), 2 fp32 NCHW (with row_off)
template<int ACT, int RES, int OUT, bool HAS_BIAS, bool NEDGE>
__global__ __launch_bounds__(256, 2) void gemm_bf16(
        const u16* __restrict__ X, const u16* __restrict__ Wt,
        const float* __restrict__ bias, const float* __restrict__ res,
        void* __restrict__ Yout, int Ncols, int K, int Nstride, int row_off){
    __shared__ u16 As[128*64];
    __shared__ u16 Bs[128*64];
    const int tid  = threadIdx.x;
    const int row0 = blockIdx.x * 128;
    const int col0 = blockIdx.y * 128;
    const int lane = tid & 63;
    const int wave = tid >> 6;
    const int wr = (wave >> 1) * 64;
    const int wc = (wave & 1) * 64;
    f32x4 acc[4][4] = {};
    const int kc  = (tid & 7) * 8;   // k element offset in 64-wide tile
    const int rA  = tid >> 3;        // 0..31
    const int kcb = kc * 2;          // byte offset
    const bf16x8 vzero = {0,0,0,0,0,0,0,0};
    for (int kt = 0; kt < K; kt += 64){
        #pragma unroll
        for (int i = 0; i < 4; i++){
            int r = rA + i*32;
            bf16x8 v = *(const bf16x8*)(X + (size_t)(row0 + r) * K + kt + kc);
            *(bf16x8*)((char*)As + r*128 + (kcb ^ ((r & 7) << 4))) = v;
        }
        #pragma unroll
        for (int i = 0; i < 4; i++){
            int r = rA + i*32;
            int gc = col0 + r;
            bf16x8 v = vzero;
            if (!NEDGE || gc < Ncols) v = *(const bf16x8*)(Wt + (size_t)gc * K + kt + kc);
            *(bf16x8*)((char*)Bs + r*128 + (kcb ^ ((r & 7) << 4))) = v;
        }
        __syncthreads();
        #pragma unroll
        for (int ks = 0; ks < 2; ks++){
            const int kb = ks*64 + ((lane >> 4) * 16);
            bf16x8 af[4], bv[4];
            #pragma unroll
            for (int m = 0; m < 4; m++){
                int r = wr + m*16 + (lane & 15);
                af[m] = *(const bf16x8*)((const char*)As + r*128 + (kb ^ ((r & 7) << 4)));
            }
            #pragma unroll
            for (int nn = 0; nn < 4; nn++){
                int r = wc + nn*16 + (lane & 15);
                bv[nn] = *(const bf16x8*)((const char*)Bs + r*128 + (kb ^ ((r & 7) << 4)));
            }
            #pragma unroll
            for (int m = 0; m < 4; m++)
                #pragma unroll
                for (int nn = 0; nn < 4; nn++)
                    acc[m][nn] = __builtin_amdgcn_mfma_f32_16x16x32_bf16(af[m], bv[nn], acc[m][nn], 0, 0, 0);
        }
        __syncthreads();
    }
    const int lr = (lane >> 4) * 4;
    const int lc = lane & 15;
    #pragma unroll
    for (int nn = 0; nn < 4; nn++){
        int gc = col0 + wc + nn*16 + lc;
        if (NEDGE && gc >= Ncols) continue;
        float bvl = HAS_BIAS ? bias[gc] : 0.f;
        #pragma unroll
        for (int m = 0; m < 4; m++){
            int nb = row0 + wr + m*16 + lr;     // local row base; rows nb..nb+3
            float4 rv;
            if (RES == 2){
                int gr = nb + row_off;
                int bb = gr >> 12, n = gr & 4095;
                rv = *(const float4*)(res + ((size_t)bb*NC + gc)*NHW + n);
            }
            float vout[4];
            #pragma unroll
            for (int r = 0; r < 4; r++){
                float v = acc[m][nn][r] + bvl;
                if (ACT == 1) v = gelu_f(v);
                else if (ACT == 2) v = softplus_f(v);
                if (RES == 1) v += res[(size_t)(nb + r + row_off) * NC + gc];
                if (RES == 2) v += ((const float*)&rv)[r];
                vout[r] = v;
            }
            if (OUT == 0){
                #pragma unroll
                for (int r = 0; r < 4; r++)
                    ((float*)Yout)[(size_t)(nb + r) * NC + gc] = vout[r];
            } else if (OUT == 1){
                #pragma unroll
                for (int r = 0; r < 4; r++)
                    ((u16*)Yout)[(size_t)(nb + r) * Nstride + gc] = f2bf(vout[r]);
            } else {
                int gr = nb + row_off;
                int bb = gr >> 12, n = gr & 4095;
                float4 o; o.x = vout[0]; o.y = vout[1]; o.z = vout[2]; o.w = vout[3];
                *(float4*)(((float*)Yout) + ((size_t)bb*NC + gc)*NHW + n) = o;
            }
        }
    }
}

// ---------------- attention: kv = K^T V (per b,h), ksum ----------------
__global__ __launch_bounds__(256) void kv_kernel(const u16* __restrict__ kbf, const u16* __restrict__ vbf,
                                                 float* __restrict__ kv, float* __restrict__ ksum){
    int bh = blockIdx.x >> 3; int chunk = blockIdx.x & 7;
    int b = bh >> 2, h = bh & 3;
    size_t base = ((size_t)b*NHW + (size_t)chunk*512) * NC + h*64;
    __shared__ float ks[64][65];
    __shared__ float vs[64][68];
    int c  = threadIdx.x & 63;
    int d0 = (threadIdx.x >> 6) * 16;
    float acc[16];
    #pragma unroll
    for (int j = 0; j < 16; j++) acc[j] = 0.f;
    float ksacc = 0.f;
    for (int t = 0; t < 8; t++){
        __syncthreads();
        #pragma unroll
        for (int i = 0; i < 16; i++){
            int idx = threadIdx.x + i*256; int nl = idx >> 6, cc = idx & 63;
            size_t gpos = base + ((size_t)t*64 + nl) * NC + cc;
            ks[nl][cc] = bf2f(kbf[gpos]);
            vs[nl][cc] = bf2f(vbf[gpos]);
        }
        __syncthreads();
        for (int nl = 0; nl < 64; nl++){
            float kvl = ks[nl][c];
            const float4* vr = (const float4*)&vs[nl][d0];
            float4 v0 = vr[0], v1 = vr[1], v2 = vr[2], v3 = vr[3];
            acc[0]+=kvl*v0.x; acc[1]+=kvl*v0.y; acc[2]+=kvl*v0.z; acc[3]+=kvl*v0.w;
            acc[4]+=kvl*v1.x; acc[5]+=kvl*v1.y; acc[6]+=kvl*v1.z; acc[7]+=kvl*v1.w;
            acc[8]+=kvl*v2.x; acc[9]+=kvl*v2.y; acc[10]+=kvl*v2.z; acc[11]+=kvl*v2.w;
            acc[12]+=kvl*v3.x; acc[13]+=kvl*v3.y; acc[14]+=kvl*v3.z; acc[15]+=kvl*v3.w;
        }
        if (threadIdx.x < 64){
            #pragma unroll 8
            for (int nl = 0; nl < 64; nl++) ksacc += ks[nl][threadIdx.x];
        }
    }
    float* kvp = kv + (size_t)bh*4096 + c*64 + d0;
    #pragma unroll
    for (int j = 0; j < 16; j++) atomicAdd(&kvp[j], acc[j]);
    if (threadIdx.x < 64) atomicAdd(&ksum[bh*64 + threadIdx.x], ksacc);
}

// out[n][d] = ((q . kv)/8 + v) * z * g  -> ao bf16
__global__ __launch_bounds__(256) void attn_out_kernel(const u16* __restrict__ qbf, const u16* __restrict__ vbf,
        const u16* __restrict__ gbf, const float* __restrict__ kv, const float* __restrict__ ksum,
        u16* __restrict__ ao){
    int bid = blockIdx.x;
    int b = bid >> 8; int h = (bid >> 6) & 3; int ncn = bid & 63;
    __shared__ float kvs[64][65];
    __shared__ float qs[64][65];
    __shared__ float zs[64];
    size_t base = ((size_t)b*NHW + ncn*64) * NC + h*64;
    const float* kvp = kv + ((size_t)(b*4 + h)) * 4096;
    #pragma unroll
    for (int i = 0; i < 16; i++){
        int idx = threadIdx.x + i*256;
        kvs[idx >> 6][idx & 63] = kvp[idx];
    }
    #pragma unroll
    for (int i = 0; i < 16; i++){
        int idx = threadIdx.x + i*256; int nl = idx >> 6, cc = idx & 63;
        qs[nl][cc] = bf2f(qbf[base + (size_t)nl*NC + cc]);
    }
    __syncthreads();
    if (threadIdx.x < 64){
        const float* kss = ksum + (b*4 + h) * 64;
        float s = 0.f;
        for (int cc = 0; cc < 64; cc++) s += qs[threadIdx.x][cc] * kss[cc];
        zs[threadIdx.x] = 1.f / (s * 0.125f + 4096.f);
    }
    __syncthreads();
    int d = threadIdx.x & 63; int ng = threadIdx.x >> 6;
    for (int nl = ng; nl < 64; nl += 4){
        float s = 0.f;
        #pragma unroll 8
        for (int cc = 0; cc < 64; cc++) s += qs[nl][cc] * kvs[cc][d];
        size_t gi = base + (size_t)nl*NC + d;
        float o = (s * 0.125f + bf2f(vbf[gi])) * zs[nl];
        ao[gi] = f2bf(o * bf2f(gbf[gi]));
    }
}

// ---------------- instance norm #2 (on [M,C] fp32 attn) ----------------
__global__ __launch_bounds__(256) void colstats_part(const float* __restrict__ a, float* __restrict__ part){
    int b = blockIdx.x >> 5, seg = blockIdx.x & 31;
    const float* p = a + ((size_t)b*NHW + seg*128) * NC + threadIdx.x;
    float s = 0.f, s2 = 0.f;
    for (int r = 0; r < 128; r++){ float v = p[(size_t)r*NC]; s += v; s2 += v*v; }
    part[((size_t)blockIdx.x*256 + threadIdx.x)*2]     = s;
    part[((size_t)blockIdx.x*256 + threadIdx.x)*2 + 1] = s2;
}
__global__ __launch_bounds__(256) void colstats_final(const float* __restrict__ part,
        float* __restrict__ mean, float* __restrict__ rstd){
    int b = blockIdx.x; int c = threadIdx.x;
    float s = 0.f, s2 = 0.f;
    for (int i = 0; i < 32; i++){
        s  += part[(((size_t)b*32 + i)*256 + c)*2];
        s2 += part[(((size_t)b*32 + i)*256 + c)*2 + 1];
    }
    float mu = s * (1.f/NHW);
    float var = s2 * (1.f/NHW) - mu*mu;
    mean[b*NC + c] = mu; rstd[b*NC + c] = rsqrtf(var + 1e-5f);
}
__global__ __launch_bounds__(256) void norm_cast(const float4* __restrict__ a, const float* __restrict__ mean,
        const float* __restrict__ rstd, u16x4* __restrict__ yn){
    for (size_t gi = (size_t)blockIdx.x*256 + threadIdx.x; gi < (size_t)(MTOT)*64; gi += (size_t)gridDim.x*256){
        float4 v = a[gi];
        int c4 = (int)(gi & 63) * 4;
        int b  = (int)(gi >> 18);
        const float* mp = mean + b*NC + c4;
        const float* rp = rstd + b*NC + c4;
        u16x4 o;
        o[0] = f2bf((v.x - mp[0]) * rp[0]);
        o[1] = f2bf((v.y - mp[1]) * rp[1]);
        o[2] = f2bf((v.z - mp[2]) * rp[2]);
        o[3] = f2bf((v.w - mp[3]) * rp[3]);
        yn[gi] = o;
    }
}

// ---------------- depthwise 3x3 + gelu-gate (4-batch chunk) ----------------
// one thread per (pixel, 8-channel group); 88 groups cover 704 output chans
__global__ __launch_bounds__(256) void dw_kernel(const u16* __restrict__ ff1, const float* __restrict__ wdt,
                                                 u16* __restrict__ ffg){
    int gid = blockIdx.x * 256 + threadIdx.x;     // 16384*88 threads
    int pix = gid / 88;
    int g   = gid - pix * 88;
    int ch0 = g * 8;
    u16* outp = ffg + (size_t)pix * KPAD + ch0;
    const bf16x8 vz = {0,0,0,0,0,0,0,0};
    if (ch0 >= NCHH){ *(bf16x8*)outp = vz; return; }
    int b  = pix >> 12;
    int yx = pix & 4095;
    int y  = yx >> 6, x = yx & 63;
    float a1[8] = {0,0,0,0,0,0,0,0};
    float a2[8] = {0,0,0,0,0,0,0,0};
    #pragma unroll
    for (int dy = -1; dy <= 1; dy++){
        int yy = y + dy; if (yy < 0 || yy >= 64) continue;
        #pragma unroll
        for (int dx = -1; dx <= 1; dx++){
            int xx = x + dx; if (xx < 0 || xx >= 64) continue;
            int wi = (dy + 1)*3 + (dx + 1);
            const float4* w1p = (const float4*)(wdt + (wi*2 + 0)*NCHH + ch0);
            const float4* w2p = (const float4*)(wdt + (wi*2 + 1)*NCHH + ch0);
            float4 w1a = w1p[0], w1b = w1p[1];
            float4 w2a = w2p[0], w2b = w2p[1];
            size_t p = ((size_t)(b << 12) + yy*64 + xx) * FF1C;
            bf16x8 v1 = *(const bf16x8*)(ff1 + p + ch0);
            bf16x8 v2 = *(const bf16x8*)(ff1 + p + NCHH + ch0);
            const float* w1s = (const float*)&w1a;
            const float* w2s = (const float*)&w2a;
            #pragma unroll
            for (int j = 0; j < 4; j++){
                a1[j] += w1s[j] * bf2f((u16)v1[j]);
                a2[j] += w2s[j] * bf2f((u16)v2[j]);
            }
            const float* w1t = (const float*)&w1b;
            const float* w2t = (const float*)&w2b;
            #pragma unroll
            for (int j = 0; j < 4; j++){
                a1[j+4] += w1t[j] * bf2f((u16)v1[j+4]);
                a2[j+4] += w2t[j] * bf2f((u16)v2[j+4]);
            }
        }
    }
    bf16x8 o;
    #pragma unroll
    for (int j = 0; j < 8; j++) o[j] = (short)f2bf(gelu_f(a1[j]) * a2[j]);
    *(bf16x8*)outp = o;
}

extern "C" void kernel_launch(void* const* d_in, const int* in_sizes, int n_in,
                              void* d_out, int out_size, void* d_ws, size_t ws_size,
                              hipStream_t stream){
    const float* x    = (const float*)d_in[0];
    const float* wq1  = (const float*)d_in[1];
    const float* wq2  = (const float*)d_in[2];
    const float* wk1  = (const float*)d_in[3];
    const float* wk2  = (const float*)d_in[4];
    const float* wv   = (const float*)d_in[5];
    const float* wg   = (const float*)d_in[6];
    const float* wo   = (const float*)d_in[7];
    const float* bq1  = (const float*)d_in[8];
    const float* bq2  = (const float*)d_in[9];
    const float* bk1  = (const float*)d_in[10];
    const float* bk2  = (const float*)d_in[11];
    const float* bv   = (const float*)d_in[12];
    const float* bg   = (const float*)d_in[13];
    const float* bo   = (const float*)d_in[14];
    const float* ffw1 = (const float*)d_in[15];
    const float* ffwd = (const float*)d_in[16];
    const float* ffw2 = (const float*)d_in[17];

    char* ws = (char*)d_ws;
    size_t off = 0;
    auto alloc = [&](size_t bytes) -> char* {
        char* p = ws + off;
        off += (bytes + 255) & ~(size_t)255;
        return p;
    };
    const size_t MC = (size_t)MTOT * NC;          // 16,777,216 elements

    u16* wq1b  = (u16*)alloc(65536*2);
    u16* wq2b  = (u16*)alloc(65536*2);
    u16* wk1b  = (u16*)alloc(65536*2);
    u16* wk2b  = (u16*)alloc(65536*2);
    u16* wvb   = (u16*)alloc(65536*2);
    u16* wgb   = (u16*)alloc(65536*2);
    u16* wob   = (u16*)alloc(65536*2);
    u16* ffw1b = (u16*)alloc((size_t)FF1C*256*2);
    u16* ffw2b = (u16*)alloc((size_t)256*KPAD*2);
    float* wdt = (float*)alloc((size_t)18*NCHH*4);     // transposed dw weights
    float* mean1 = (float*)alloc(4096*4);
    float* rstd1 = (float*)alloc(4096*4);
    float* mean2 = (float*)alloc(4096*4);
    float* rstd2 = (float*)alloc(4096*4);
    float* part  = (float*)alloc((size_t)512*256*2*4);
    float* kv    = (float*)alloc((size_t)64*4096*4);   // 1 MB, 256-aligned
    float* ksum  = (float*)alloc(4096*4);              // contiguous after kv
    float* attn  = (float*)alloc(MC*4);                // 64 MB fp32 [M,C]
    // 4-slot bf16 pool, 32 MB each (128 MB total)
    char* pool = alloc((size_t)4 * MC * 2);
    u16* s1 = (u16*)pool;            // xn -> ao -> yn
    u16* s2 = s1 + MC;               // kpre -> v ; later ff1c start
    u16* s3 = s2 + MC;               // k -> qpre -> g
    u16* s4 = s3 + MC;               // q ; later part of ffg region
    u16* xn = s1,  *ao = s1,  *yn = s1;
    u16* ff1c = s2;                                    // 16384*1360*2 = 44.5 MB (spans s2 + part of s3)
    u16* ffgc = (u16*)(pool + (size_t)80*1024*1024);   // 16384*704*2 = 23 MB (inside s3/s4, after ff1c)

    (void)ws_size; (void)in_sizes; (void)n_in; (void)out_size;

    // weights -> bf16 (+ transposed dw weights fp32)
    cvt_w<<<256, 256, 0, stream>>>(wq1, wq1b, 65536);
    cvt_w<<<256, 256, 0, stream>>>(wq2, wq2b, 65536);
    cvt_w<<<256, 256, 0, stream>>>(wk1, wk1b, 65536);
    cvt_w<<<256, 256, 0, stream>>>(wk2, wk2b, 65536);
    cvt_w<<<256, 256, 0, stream>>>(wv,  wvb,  65536);
    cvt_w<<<256, 256, 0, stream>>>(wg,  wgb,  65536);
    cvt_w<<<256, 256, 0, stream>>>(wo,  wob,  65536);
    cvt_w<<<(FF1C*256+255)/256, 256, 0, stream>>>(ffw1, ffw1b, FF1C*256);
    cvt_w2pad<<<(256*KPAD+255)/256, 256, 0, stream>>>(ffw2, ffw2b);
    cvt_wdt<<<(FF1C*9+255)/256, 256, 0, stream>>>(ffwd, wdt);

    // instance norm #1 + transpose to [M,C] bf16
    inorm_stats<<<4096, 256, 0, stream>>>(x, mean1, rstd1);
    transpose_norm<<<4096, 256, 0, stream>>>(x, mean1, rstd1, xn);

    // zero kv+ksum (contiguous: 262144 + 4096 floats)
    zero_buf<<<(266240+255)/256, 256, 0, stream>>>(kv, 266240);

    // attention branch: k-chain, v, kv, q-chain, g  (4-slot schedule)
    gemm_bf16<1,0,1,true,false><<<dim3(512,2), 256, 0, stream>>>(xn, wk1b, bk1, nullptr, s2, 256, 256, 256, 0); // kpre->s2
    gemm_bf16<2,0,1,true,false><<<dim3(512,2), 256, 0, stream>>>(s2, wk2b, bk2, nullptr, s3, 256, 256, 256, 0); // k->s3
    gemm_bf16<1,0,1,true,false><<<dim3(512,2), 256, 0, stream>>>(xn, wvb,  bv,  nullptr, s2, 256, 256, 256, 0); // v->s2
    kv_kernel<<<512, 256, 0, stream>>>(s3, s2, kv, ksum);                                                        // k,v
    gemm_bf16<1,0,1,true,false><<<dim3(512,2), 256, 0, stream>>>(xn, wq1b, bq1, nullptr, s3, 256, 256, 256, 0); // qpre->s3
    gemm_bf16<2,0,1,true,false><<<dim3(512,2), 256, 0, stream>>>(s3, wq2b, bq2, nullptr, s4, 256, 256, 256, 0); // q->s4
    gemm_bf16<1,0,1,true,false><<<dim3(512,2), 256, 0, stream>>>(xn, wgb,  bg,  nullptr, s3, 256, 256, 256, 0); // g->s3
    attn_out_kernel<<<4096, 256, 0, stream>>>(s4, s2, s3, kv, ksum, ao);                                         // q,v,g -> ao(s1)

    // wo conv + bias + residual(x, NCHW direct) -> attn fp32 [M,C]
    gemm_bf16<0,2,0,true,false><<<dim3(512,2), 256, 0, stream>>>(ao, wob, bo, x, attn, 256, 256, 256, 0);

    // instance norm #2
    colstats_part<<<512, 256, 0, stream>>>(attn, part);
    colstats_final<<<16, 256, 0, stream>>>(part, mean2, rstd2);
    norm_cast<<<4096, 256, 0, stream>>>((const float4*)attn, mean2, rstd2, (u16x4*)yn);

    // FeedForward in 4 chunks of 4 batches (16384 rows each)
    for (int c = 0; c < 4; c++){
        const u16* ync = yn + (size_t)c * MCHUNK * NC;
        gemm_bf16<0,0,1,false,true><<<dim3(128,11), 256, 0, stream>>>(ync, ffw1b, nullptr, nullptr, ff1c, FF1C, 256, FF1C, 0);
        dw_kernel<<<(MCHUNK*88)/256, 256, 0, stream>>>(ff1c, wdt, ffgc);
        gemm_bf16<0,1,2,false,false><<<dim3(128,2), 256, 0, stream>>>(ffgc, ffw2b, nullptr, attn, (float*)d_out, 256, KPAD, 256, c*MCHUNK);
    }
}